// Round 1
// baseline (818.466 us; speedup 1.0000x reference)
//
#include <hip/hip_runtime.h>
#include <cstdint>
#include <cstddef>

// ---- problem constants ----
// B=2 N=512 D=384 E=128 H=8 SK=SV=16 PK=PV=4 DH=768 CAT=1280
constexpr float SCALAR_SCALE = 0.14433756729740643f;  // (3*16)^-0.5
constexpr float POINT_SCALE  = 0.13608276348795434f;  // (3*4*4.5)^-0.5
constexpr float PAIR_SCALE   = 0.57735026918962576f;  // 3^-0.5

// =====================================================================
// K1: projections. 8 tokens per block, 256 threads.
// outputs: qs[b][i][h][d] (g*128+c), ks/vs[b][h][j][d], qp[g*96+idx], kp/vp[b][h][j][p][c]
// =====================================================================
__global__ __launch_bounds__(256) void k_proj(
    const float* __restrict__ node, const float* __restrict__ rot, const float* __restrict__ trans,
    const float* __restrict__ Wq, const float* __restrict__ Wk, const float* __restrict__ Wv,
    const float* __restrict__ Wpq, const float* __restrict__ Wpk, const float* __restrict__ Wpv,
    float* __restrict__ qs, float* __restrict__ ks, float* __restrict__ vs,
    float* __restrict__ qp, float* __restrict__ kp, float* __restrict__ vp)
{
    __shared__ float xs[8*384];
    __shared__ float rawp[8*288];
    __shared__ float rots[8*9];
    __shared__ float trs[8*3];
    const int t = threadIdx.x;
    const int g0 = blockIdx.x * 8;

    const float4* nf4 = reinterpret_cast<const float4*>(node + (size_t)g0*384);
    float4* xs4 = reinterpret_cast<float4*>(xs);
    #pragma unroll
    for (int k = 0; k < 3; k++) xs4[t + k*256] = nf4[t + k*256];
    if (t < 72) rots[t] = rot[g0*9 + t];
    if (t < 24) trs[t]  = trans[g0*3 + t];
    __syncthreads();

    for (int p = 0; p < 3; p++) {
        int c = t + p*256;
        if (c < 672) {
            const float* W; int cm, ldw;
            if (c < 384) { int m = c >> 7; W = (m==0)?Wq:((m==1)?Wk:Wv); cm = c & 127; ldw = 128; }
            else { int pc = c - 384; int m = pc/96; W = (m==0)?Wpq:((m==1)?Wpk:Wpv); cm = pc%96; ldw = 96; }
            float acc[8];
            #pragma unroll
            for (int r = 0; r < 8; r++) acc[r] = 0.f;
            for (int d = 0; d < 384; d++) {
                float w = W[d*ldw + cm];
                #pragma unroll
                for (int r = 0; r < 8; r++) acc[r] += xs[r*384 + d] * w;
            }
            if (c < 384) {
                for (int r = 0; r < 8; r++) {
                    int g = g0 + r, b = g >> 9, i = g & 511;
                    if (c < 128) qs[(size_t)g*128 + c] = acc[r];
                    else if (c < 256) { int h=(c-128)>>4, d=(c-128)&15; ks[(((size_t)(b*8+h))*512 + i)*16 + d] = acc[r]; }
                    else              { int h=(c-256)>>4, d=(c-256)&15; vs[(((size_t)(b*8+h))*512 + i)*16 + d] = acc[r]; }
                }
            } else {
                int pc = c - 384;
                for (int r = 0; r < 8; r++) rawp[r*288 + pc] = acc[r];
            }
        }
    }
    __syncthreads();
    // rotate + translate point projections
    for (int k = 0; k < 9; k++) {
        int o = t + k*256;
        if (o < 2304) {
            int r = o / 288, pc = o % 288;
            int which = pc / 96, idx = pc % 96;
            int h = idx / 12, rem = idx % 12, pp = rem / 3, rr = rem % 3;
            const float* rw = &rawp[r*288 + which*96 + h*12 + pp*3];
            const float* rm = &rots[r*9];
            float v = rw[0]*rm[0*3+rr] + rw[1]*rm[1*3+rr] + rw[2]*rm[2*3+rr] + trs[r*3 + rr];
            int g = g0 + r, b = g >> 9, i = g & 511;
            if (which == 0)      qp[(size_t)g*96 + idx] = v;
            else if (which == 1) kp[((((size_t)(b*8+h))*512 + i)*4 + pp)*3 + rr] = v;
            else                 vp[((((size_t)(b*8+h))*512 + i)*4 + pp)*3 + rr] = v;
        }
    }
}

// =====================================================================
// K2: per-row attention. block = (b,i), 512 threads (8 waves, wave h).
// Phase A: stage edge chunks (64 j x 128 d, pad 129) -> logits -> softmax.
// Phase B: restage chunks (L2/L3 hit) -> res_e accumulation.
// =====================================================================
__global__ __launch_bounds__(512) void k_attn(
    const float* __restrict__ edge, const float* __restrict__ qs,
    const float* __restrict__ ks, const float* __restrict__ qp, const float* __restrict__ kp,
    const float* __restrict__ pt_w, const float* __restrict__ Wpb, const float* __restrict__ bpb,
    float* __restrict__ attn_g, float* __restrict__ cat)
{
    __shared__ float ech[64*129];
    __shared__ float attL[8*512];
    __shared__ float wpbL[128*8];
    __shared__ float qsL[128];
    __shared__ float qpL[96];
    __shared__ float pwL[8];
    __shared__ float bpbL[8];

    const int t = threadIdx.x;
    const int g = blockIdx.x, b = g >> 9, i = g & 511;

    wpbL[t] = Wpb[t];
    wpbL[t + 512] = Wpb[t + 512];
    if (t < 128) qsL[t] = qs[(size_t)g*128 + t];
    else if (t < 224) qpL[t-128] = qp[(size_t)g*96 + (t-128)];
    else if (t < 232) { float x = pt_w[t-224]; pwL[t-224] = (x > 20.f) ? x : log1pf(expf(x)); }
    else if (t < 240) bpbL[t-232] = bpb[t-232];
    __syncthreads();

    const int h = t >> 6, lane = t & 63;
    const float pwv  = pwL[h] * 0.5f * POINT_SCALE;
    const float bpbv = bpbL[h];
    float qf[16];
    #pragma unroll
    for (int d = 0; d < 16; d++) qf[d] = qsL[h*16 + d];
    float qpf[12];
    #pragma unroll
    for (int c = 0; c < 12; c++) qpf[c] = qpL[h*12 + c];

    const float4* ef4 = reinterpret_cast<const float4*>(edge) + (size_t)g*16384;

    float l[8];
    for (int cc = 0; cc < 8; cc++) {
        #pragma unroll
        for (int k = 0; k < 4; k++) {
            int i4 = t + k*512;
            float4 v = ef4[cc*2048 + i4];
            int j = i4 >> 5, d = (i4 & 31) * 4;
            float* p = &ech[j*129 + d];
            p[0]=v.x; p[1]=v.y; p[2]=v.z; p[3]=v.w;
        }
        __syncthreads();
        int j = cc*64 + lane;
        const float* er = &ech[lane*129];
        float b0=0.f, b1=0.f, b2=0.f, b3=0.f;
        #pragma unroll 8
        for (int d = 0; d < 128; d += 4) {
            b0 += er[d+0]*wpbL[(d+0)*8 + h];
            b1 += er[d+1]*wpbL[(d+1)*8 + h];
            b2 += er[d+2]*wpbL[(d+2)*8 + h];
            b3 += er[d+3]*wpbL[(d+3)*8 + h];
        }
        float bias = (b0+b1) + (b2+b3);
        const float4* kr4 = reinterpret_cast<const float4*>(ks + (((size_t)(b*8+h))*512 + j)*16);
        float qk = 0.f;
        #pragma unroll
        for (int q = 0; q < 4; q++) {
            float4 kv = kr4[q];
            qk += qf[q*4+0]*kv.x + qf[q*4+1]*kv.y + qf[q*4+2]*kv.z + qf[q*4+3]*kv.w;
        }
        const float4* kp4 = reinterpret_cast<const float4*>(kp + (((size_t)(b*8+h))*512 + j)*12);
        float dist = 0.f;
        #pragma unroll
        for (int q = 0; q < 3; q++) {
            float4 kv = kp4[q];
            float d0 = qpf[q*4+0]-kv.x, d1 = qpf[q*4+1]-kv.y, d2 = qpf[q*4+2]-kv.z, d3 = qpf[q*4+3]-kv.w;
            dist += d0*d0 + d1*d1 + d2*d2 + d3*d3;
        }
        l[cc] = qk*SCALAR_SCALE - pwv*dist + (bias + bpbv)*PAIR_SCALE;
        __syncthreads();
    }

    // wave softmax over 512 j (8 regs x 64 lanes)
    float m = l[0];
    #pragma unroll
    for (int cc = 1; cc < 8; cc++) m = fmaxf(m, l[cc]);
    #pragma unroll
    for (int off = 1; off < 64; off <<= 1) m = fmaxf(m, __shfl_xor(m, off));
    float e[8], s = 0.f;
    #pragma unroll
    for (int cc = 0; cc < 8; cc++) { e[cc] = __expf(l[cc] - m); s += e[cc]; }
    #pragma unroll
    for (int off = 1; off < 64; off <<= 1) s += __shfl_xor(s, off);
    float inv = 1.f / s;
    size_t abase = (((size_t)(b*8+h))*512 + i)*512;
    #pragma unroll
    for (int cc = 0; cc < 8; cc++) {
        float p = e[cc] * inv;
        attL[h*512 + cc*64 + lane] = p;
        attn_g[abase + cc*64 + lane] = p;
    }
    __syncthreads();

    // Phase B: res_e[h][lane], res_e[h][lane+64]
    float r0 = 0.f, r1 = 0.f;
    for (int cc = 0; cc < 8; cc++) {
        #pragma unroll
        for (int k = 0; k < 4; k++) {
            int i4 = t + k*512;
            float4 v = ef4[cc*2048 + i4];
            int j = i4 >> 5, d = (i4 & 31) * 4;
            float* p = &ech[j*129 + d];
            p[0]=v.x; p[1]=v.y; p[2]=v.z; p[3]=v.w;
        }
        __syncthreads();
        const float* al = &attL[h*512 + cc*64];
        #pragma unroll 8
        for (int jj = 0; jj < 64; jj++) {
            float a = al[jj];
            r0 += a * ech[jj*129 + lane];
            r1 += a * ech[jj*129 + 64 + lane];
        }
        __syncthreads();
    }
    float* cr = cat + (size_t)g*1280 + 256 + h*128;
    cr[lane] = r0;
    cr[64 + lane] = r1;
}

// =====================================================================
// K3: res_s, res_p (rotate back), res_pn from stored attn probs.
// block = (b,i), 256 threads.
// =====================================================================
__global__ __launch_bounds__(256) void k_resv(
    const float* __restrict__ attn_g, const float* __restrict__ vs, const float* __restrict__ vp,
    const float* __restrict__ rot, const float* __restrict__ trans, float* __restrict__ cat)
{
    __shared__ float attL[8*516];
    __shared__ float rpL[96];
    __shared__ float rpsL[96];
    const int t = threadIdx.x, g = blockIdx.x, b = g >> 9, i = g & 511;

    #pragma unroll
    for (int k = 0; k < 4; k++) {
        int i4 = t + k*256;               // 0..1023 float4s
        int h = i4 >> 7, jd4 = i4 & 127;
        float4 v = reinterpret_cast<const float4*>(attn_g)[(((size_t)(b*8+h))*512 + i)*128 + jd4];
        *reinterpret_cast<float4*>(&attL[h*516 + jd4*4]) = v;
    }
    __syncthreads();

    if (t < 224) {
        const float* vsrc; int stride, h;
        if (t < 128) { h = t >> 4; int o = t & 15; vsrc = vs + (((size_t)(b*8+h))*512)*16 + o; stride = 16; }
        else { int idx = t - 128; h = idx / 12; int o = idx % 12; vsrc = vp + (((size_t)(b*8+h))*512)*12 + o; stride = 12; }
        const float* al = &attL[h*516];
        float a0=0.f, a1=0.f, a2=0.f, a3=0.f;
        for (int j = 0; j < 512; j += 4) {
            a0 += al[j+0]*vsrc[(size_t)(j+0)*stride];
            a1 += al[j+1]*vsrc[(size_t)(j+1)*stride];
            a2 += al[j+2]*vsrc[(size_t)(j+2)*stride];
            a3 += al[j+3]*vsrc[(size_t)(j+3)*stride];
        }
        float acc = (a0+a1) + (a2+a3);
        if (t < 128) cat[(size_t)g*1280 + t] = acc;
        else rpL[t-128] = acc;
    }
    __syncthreads();
    if (t < 96) {
        int h = t/12, rem = t%12, p = rem/3, rr = rem%3;
        const float* rp = &rpL[h*12 + p*3];
        const float* rm = rot + (size_t)g*9 + rr*3;   // rot[b,i,rr,c]
        const float* tr = trans + (size_t)g*3;
        float v = (rp[0]-tr[0])*rm[0] + (rp[1]-tr[1])*rm[1] + (rp[2]-tr[2])*rm[2];
        rpsL[t] = v;
        cat[(size_t)g*1280 + 128 + t] = v;
    }
    __syncthreads();
    if (t < 32) {
        int h = t >> 2, p = t & 3;
        const float* v = &rpsL[h*12 + p*3];
        cat[(size_t)g*1280 + 224 + t] = sqrtf(v[0]*v[0] + v[1]*v[1] + v[2]*v[2] + 1e-8f);
    }
}

// =====================================================================
// K4: tiled f32 GEMM  C[M,N] = A[M,K] @ W[K,N] + bias (opt relu)
// BM=BN=64, BK=16, 256 threads, 4x4 micro-tile.
// =====================================================================
template<bool RELU>
__global__ __launch_bounds__(256) void k_gemm(
    const float* __restrict__ A, const float* __restrict__ W, const float* __restrict__ bias,
    float* __restrict__ C, int M, int Ncol, int K)
{
    __shared__ float At[16*68];   // [k][m], padded
    __shared__ float Bt[16*64];   // [k][n]
    const int t = threadIdx.x;
    const int ntile = Ncol >> 6;
    const int m0 = (blockIdx.x / ntile) << 6;
    const int n0 = (blockIdx.x % ntile) << 6;
    const int tx = t & 15, ty = t >> 4;
    const int arow = t >> 2, ak = (t & 3) * 4;
    const int brow = t >> 4, bn = (t & 15) * 4;
    float acc[4][4] = {};
    for (int k0 = 0; k0 < K; k0 += 16) {
        float4 a4 = *reinterpret_cast<const float4*>(A + (size_t)(m0+arow)*K + k0 + ak);
        float4 b4 = *reinterpret_cast<const float4*>(W + (size_t)(k0+brow)*Ncol + n0 + bn);
        At[(ak+0)*68 + arow] = a4.x;
        At[(ak+1)*68 + arow] = a4.y;
        At[(ak+2)*68 + arow] = a4.z;
        At[(ak+3)*68 + arow] = a4.w;
        *reinterpret_cast<float4*>(&Bt[brow*64 + bn]) = b4;
        __syncthreads();
        #pragma unroll
        for (int kk = 0; kk < 16; kk++) {
            float4 av = *reinterpret_cast<const float4*>(&At[kk*68 + ty*4]);
            float4 bv = *reinterpret_cast<const float4*>(&Bt[kk*64 + tx*4]);
            float am[4] = {av.x, av.y, av.z, av.w};
            float bw[4] = {bv.x, bv.y, bv.z, bv.w};
            #pragma unroll
            for (int mi = 0; mi < 4; mi++)
                #pragma unroll
                for (int ni = 0; ni < 4; ni++) acc[mi][ni] += am[mi] * bw[ni];
        }
        __syncthreads();
    }
    float4 bb = *reinterpret_cast<const float4*>(bias + n0 + tx*4);
    float bias4[4] = {bb.x, bb.y, bb.z, bb.w};
    #pragma unroll
    for (int mi = 0; mi < 4; mi++) {
        int row = m0 + ty*4 + mi;
        float4 o;
        float vv[4];
        #pragma unroll
        for (int ni = 0; ni < 4; ni++) {
            float v = acc[mi][ni] + bias4[ni];
            if (RELU) v = fmaxf(v, 0.f);
            vv[ni] = v;
        }
        o.x = vv[0]; o.y = vv[1]; o.z = vv[2]; o.w = vv[3];
        *reinterpret_cast<float4*>(C + (size_t)row*Ncol + n0 + tx*4) = o;
    }
}

// =====================================================================
// K5: LayerNorm over D=384. 1 wave per row.
// =====================================================================
__global__ __launch_bounds__(64) void k_ln(
    const float* __restrict__ X, const float* __restrict__ gam, const float* __restrict__ bet,
    float* __restrict__ Y)
{
    const int t = threadIdx.x, g = blockIdx.x;
    const float* x = X + (size_t)g*384;
    float v[6]; float s = 0.f, s2 = 0.f;
    #pragma unroll
    for (int k = 0; k < 6; k++) { v[k] = x[t + 64*k]; s += v[k]; s2 += v[k]*v[k]; }
    #pragma unroll
    for (int off = 1; off < 64; off <<= 1) { s += __shfl_xor(s, off); s2 += __shfl_xor(s2, off); }
    float mu = s * (1.f/384.f);
    float var = s2 * (1.f/384.f) - mu*mu;
    float rs = rsqrtf(var + 1e-5f);
    float* y = Y + (size_t)g*384;
    #pragma unroll
    for (int k = 0; k < 6; k++) { int d = t + 64*k; y[d] = (v[k]-mu)*rs*gam[d] + bet[d]; }
}

// =====================================================================
extern "C" void kernel_launch(void* const* d_in, const int* in_sizes, int n_in,
                              void* d_out, int out_size, void* d_ws, size_t ws_size,
                              hipStream_t stream)
{
    const float* node = (const float*)d_in[0];
    const float* edge = (const float*)d_in[1];
    const float* rot  = (const float*)d_in[2];
    const float* trans= (const float*)d_in[3];
    // d_in[4] = mask (all true) -- unused
    const float* Wq  = (const float*)d_in[5];
    const float* Wk  = (const float*)d_in[6];
    const float* Wv  = (const float*)d_in[7];
    const float* Wpq = (const float*)d_in[8];
    const float* Wpk = (const float*)d_in[9];
    const float* Wpv = (const float*)d_in[10];
    const float* pt_w= (const float*)d_in[11];
    const float* Wpb = (const float*)d_in[12];
    const float* bpb = (const float*)d_in[13];
    const float* Wo  = (const float*)d_in[14];
    const float* bo  = (const float*)d_in[15];
    const float* ln1g= (const float*)d_in[16];
    const float* ln1b= (const float*)d_in[17];
    const float* W1  = (const float*)d_in[18];
    const float* b1  = (const float*)d_in[19];
    const float* W2  = (const float*)d_in[20];
    const float* b2  = (const float*)d_in[21];
    const float* W3  = (const float*)d_in[22];
    const float* b3  = (const float*)d_in[23];
    const float* ln2g= (const float*)d_in[24];
    const float* ln2b= (const float*)d_in[25];

    float* ws = (float*)d_ws;
    float* qs   = ws;                 // 131072
    float* ks   = qs + 131072;        // 131072
    float* vs   = ks + 131072;        // 131072
    float* qp   = vs + 131072;        // 98304
    float* kp   = qp + 98304;         // 98304
    float* vp   = kp + 98304;         // 98304
    float* attn = vp + 98304;         // 4194304 (16.8 MB)
    float* cat  = attn + 4194304;     // 1310720
    // MLP intermediates overlaid on attn region (attn dead after k_resv)
    float* x0  = attn;                // 393216
    float* xln = attn + 393216;       // 393216
    float* h1  = attn + 786432;       // 786432
    float* h2  = attn + 1572864;      // 786432
    float* x3  = attn + 2359296;      // 393216  (ends 2752512 < 4194304)
    float* out = (float*)d_out;

    k_proj<<<128, 256, 0, stream>>>(node, rot, trans, Wq, Wk, Wv, Wpq, Wpk, Wpv,
                                    qs, ks, vs, qp, kp, vp);
    k_attn<<<1024, 512, 0, stream>>>(edge, qs, ks, qp, kp, pt_w, Wpb, bpb, attn, cat);
    k_resv<<<1024, 256, 0, stream>>>(attn, vs, vp, rot, trans, cat);
    k_gemm<false><<<16*6,  256, 0, stream>>>(cat, Wo, bo, x0, 1024, 384, 1280);
    k_ln<<<1024, 64, 0, stream>>>(x0, ln1g, ln1b, xln);
    k_gemm<true ><<<16*12, 256, 0, stream>>>(xln, W1, b1, h1, 1024, 768, 384);
    k_gemm<true ><<<16*12, 256, 0, stream>>>(h1, W2, b2, h2, 1024, 768, 768);
    k_gemm<false><<<16*6,  256, 0, stream>>>(h2, W3, b3, x3, 1024, 384, 768);
    k_ln<<<1024, 64, 0, stream>>>(x3, ln2g, ln2b, out);
}

// Round 8
// 720.659 us; speedup vs baseline: 1.1357x; 1.1357x over previous
//
#include <hip/hip_runtime.h>
#include <cstdint>
#include <cstddef>

// ---- problem constants ----
// B=2 N=512 D=384 E=128 H=8 SK=SV=16 PK=PV=4 DH=768 CAT=1280
constexpr float SCALAR_SCALE = 0.14433756729740643f;  // (3*16)^-0.5
constexpr float POINT_SCALE  = 0.13608276348795434f;  // (3*4*4.5)^-0.5
constexpr float PAIR_SCALE   = 0.57735026918962576f;  // 3^-0.5

typedef float  f32x4  __attribute__((ext_vector_type(4)));
typedef short  bf16x8 __attribute__((ext_vector_type(8)));
typedef unsigned short us8 __attribute__((ext_vector_type(8)));
typedef unsigned short us4 __attribute__((ext_vector_type(4)));

__device__ __forceinline__ unsigned short f2b(float f) {
    union { float f; uint32_t u; } v; v.f = f;
    uint32_t u = v.u;
    return (unsigned short)((u + 0x7FFFu + ((u >> 16) & 1u)) >> 16);
}

// =====================================================================
// K0: weight prep — W[K][N] f32 -> Wt[N][K] bf16 (32x32 tiles)
// =====================================================================
__global__ __launch_bounds__(256) void k_prepw(
    const float* __restrict__ W, unsigned short* __restrict__ Wt, int K, int N)
{
    __shared__ float L[32][33];
    const int ntile = N >> 5;
    const int kt = (blockIdx.x / ntile) << 5;
    const int nt = (blockIdx.x % ntile) << 5;
    const int t = threadIdx.x;
    const int row = t >> 3, col4 = (t & 7) * 4;
    float4 v = *reinterpret_cast<const float4*>(W + (size_t)(kt + row) * N + nt + col4);
    L[row][col4+0] = v.x; L[row][col4+1] = v.y; L[row][col4+2] = v.z; L[row][col4+3] = v.w;
    __syncthreads();
    us4 o;
    o[0] = f2b(L[col4+0][row]);
    o[1] = f2b(L[col4+1][row]);
    o[2] = f2b(L[col4+2][row]);
    o[3] = f2b(L[col4+3][row]);
    *reinterpret_cast<us4*>(Wt + (size_t)(nt + row) * K + kt + col4) = o;
}

// =====================================================================
// K1: projections. 8 tokens per block, 256 threads.
// =====================================================================
__global__ __launch_bounds__(256) void k_proj(
    const float* __restrict__ node, const float* __restrict__ rot, const float* __restrict__ trans,
    const float* __restrict__ Wq, const float* __restrict__ Wk, const float* __restrict__ Wv,
    const float* __restrict__ Wpq, const float* __restrict__ Wpk, const float* __restrict__ Wpv,
    float* __restrict__ qs, float* __restrict__ ks, float* __restrict__ vs,
    float* __restrict__ qp, float* __restrict__ kp, float* __restrict__ vp)
{
    __shared__ float xs[8*384];
    __shared__ float rawp[8*288];
    __shared__ float rots[8*9];
    __shared__ float trs[8*3];
    const int t = threadIdx.x;
    const int g0 = blockIdx.x * 8;

    const float4* nf4 = reinterpret_cast<const float4*>(node + (size_t)g0*384);
    float4* xs4 = reinterpret_cast<float4*>(xs);
    #pragma unroll
    for (int k = 0; k < 3; k++) xs4[t + k*256] = nf4[t + k*256];
    if (t < 72) rots[t] = rot[g0*9 + t];
    if (t < 24) trs[t]  = trans[g0*3 + t];
    __syncthreads();

    for (int p = 0; p < 3; p++) {
        int c = t + p*256;
        if (c < 672) {
            const float* W; int cm, ldw;
            if (c < 384) { int m = c >> 7; W = (m==0)?Wq:((m==1)?Wk:Wv); cm = c & 127; ldw = 128; }
            else { int pc = c - 384; int m = pc/96; W = (m==0)?Wpq:((m==1)?Wpk:Wpv); cm = pc%96; ldw = 96; }
            float acc[8];
            #pragma unroll
            for (int r = 0; r < 8; r++) acc[r] = 0.f;
            for (int d = 0; d < 384; d++) {
                float w = W[d*ldw + cm];
                #pragma unroll
                for (int r = 0; r < 8; r++) acc[r] += xs[r*384 + d] * w;
            }
            if (c < 384) {
                for (int r = 0; r < 8; r++) {
                    int g = g0 + r, b = g >> 9, i = g & 511;
                    if (c < 128) qs[(size_t)g*128 + c] = acc[r];
                    else if (c < 256) { int h=(c-128)>>4, d=(c-128)&15; ks[(((size_t)(b*8+h))*512 + i)*16 + d] = acc[r]; }
                    else              { int h=(c-256)>>4, d=(c-256)&15; vs[(((size_t)(b*8+h))*512 + i)*16 + d] = acc[r]; }
                }
            } else {
                int pc = c - 384;
                for (int r = 0; r < 8; r++) rawp[r*288 + pc] = acc[r];
            }
        }
    }
    __syncthreads();
    for (int k = 0; k < 9; k++) {
        int o = t + k*256;
        if (o < 2304) {
            int r = o / 288, pc = o % 288;
            int which = pc / 96, idx = pc % 96;
            int h = idx / 12, rem = idx % 12, pp = rem / 3, rr = rem % 3;
            const float* rw = &rawp[r*288 + which*96 + h*12 + pp*3];
            const float* rm = &rots[r*9];
            float v = rw[0]*rm[0*3+rr] + rw[1]*rm[1*3+rr] + rw[2]*rm[2*3+rr] + trs[r*3 + rr];
            int g = g0 + r, b = g >> 9, i = g & 511;
            if (which == 0)      qp[(size_t)g*96 + idx] = v;
            else if (which == 1) kp[((((size_t)(b*8+h))*512 + i)*4 + pp)*3 + rr] = v;
            else                 vp[((((size_t)(b*8+h))*512 + i)*4 + pp)*3 + rr] = v;
        }
    }
}

// =====================================================================
// K2: fused attention. block=(b,i), 512 threads (wave = head h).
// Single pass over edge with online softmax; res_s/res_p/res_pn/res_e
// all accumulated in-kernel. Edge chunks reg-double-buffered (T14).
// =====================================================================
__global__ __launch_bounds__(512) void k_attn(
    const float* __restrict__ edge, const float* __restrict__ qs,
    const float* __restrict__ ks, const float* __restrict__ qp, const float* __restrict__ kp,
    const float* __restrict__ vs, const float* __restrict__ vp,
    const float* __restrict__ rot, const float* __restrict__ trans,
    const float* __restrict__ pt_w, const float* __restrict__ Wpb, const float* __restrict__ bpb,
    float* __restrict__ cat)
{
    __shared__ __align__(16) float ech[64*132];   // 64 j x 128 d, stride 132
    __shared__ float attE[8*64];
    __shared__ float wpbL[128*8];
    __shared__ float qsL[128];
    __shared__ float qpL[96];
    __shared__ float pwL[8];
    __shared__ float bpbL[8];
    __shared__ float rpL[96];
    __shared__ float rpsL[96];

    const int t = threadIdx.x;
    const int g = blockIdx.x, b = g >> 9;

    wpbL[t] = Wpb[t];
    wpbL[t + 512] = Wpb[t + 512];
    if (t < 128) qsL[t] = qs[(size_t)g*128 + t] * SCALAR_SCALE;
    else if (t < 224) qpL[t-128] = qp[(size_t)g*96 + (t-128)];
    else if (t < 232) { float x = pt_w[t-224]; pwL[t-224] = (x > 20.f) ? x : log1pf(expf(x)); }
    else if (t < 240) bpbL[t-232] = bpb[t-232];
    __syncthreads();

    const int h = t >> 6, lane = t & 63;
    const float pwv  = pwL[h] * 0.5f * POINT_SCALE;
    const float bpbv = bpbL[h];
    float qf[16];
    #pragma unroll
    for (int d = 0; d < 16; d++) qf[d] = qsL[h*16 + d];
    float qpf[12];
    #pragma unroll
    for (int c = 0; c < 12; c++) qpf[c] = qpL[h*12 + c];

    const float4* ef4 = reinterpret_cast<const float4*>(edge) + (size_t)g*16384;
    const float4* kr4 = reinterpret_cast<const float4*>(ks + (((size_t)(b*8+h))*512)*16);
    const float*  kpb = kp + (((size_t)(b*8+h))*512)*12;

    // v-source for res_s (lanes 0..15) / res_p (lanes 16..27)
    const float* vsrc = nullptr; int vstride = 0;
    if (lane < 16)      { vsrc = vs + (((size_t)(b*8+h))*512)*16 + lane;      vstride = 16; }
    else if (lane < 28) { vsrc = vp + (((size_t)(b*8+h))*512)*12 + (lane-16); vstride = 12; }

    // prologue: chunk 0 into regs
    float4 rv[4];
    #pragma unroll
    for (int k = 0; k < 4; k++) rv[k] = ef4[t + k*512];

    float m = -1e30f, s = 0.f, r0 = 0.f, r1 = 0.f, rsv = 0.f;

    for (int cc = 0; cc < 8; cc++) {
        // write staged chunk to LDS
        #pragma unroll
        for (int k = 0; k < 4; k++) {
            int i4 = t + k*512;
            int j = i4 >> 5, d4 = i4 & 31;
            *reinterpret_cast<float4*>(&ech[j*132 + d4*4]) = rv[k];
        }
        // issue next chunk's loads (in flight across barrier + compute)
        if (cc < 7) {
            #pragma unroll
            for (int k = 0; k < 4; k++) rv[k] = ef4[(cc+1)*2048 + t + k*512];
        }
        __syncthreads();

        const int j = cc*64 + lane;
        // pair bias: edge[j,:] . Wpb[:,h]
        const float4* er4 = reinterpret_cast<const float4*>(&ech[lane*132]);
        float b0=0.f, b1=0.f, b2=0.f, b3=0.f;
        #pragma unroll 8
        for (int d4 = 0; d4 < 32; d4++) {
            float4 e = er4[d4];
            b0 += e.x * wpbL[(d4*4+0)*8 + h];
            b1 += e.y * wpbL[(d4*4+1)*8 + h];
            b2 += e.z * wpbL[(d4*4+2)*8 + h];
            b3 += e.w * wpbL[(d4*4+3)*8 + h];
        }
        float bias = (b0+b1) + (b2+b3);
        // scalar qk (qf prescaled)
        float qk = 0.f;
        #pragma unroll
        for (int q = 0; q < 4; q++) {
            float4 kv = kr4[j*4 + q];
            qk += qf[q*4+0]*kv.x + qf[q*4+1]*kv.y + qf[q*4+2]*kv.z + qf[q*4+3]*kv.w;
        }
        // point distance
        const float4* kp4 = reinterpret_cast<const float4*>(kpb + j*12);
        float dist = 0.f;
        #pragma unroll
        for (int q = 0; q < 3; q++) {
            float4 kv = kp4[q];
            float d0 = qpf[q*4+0]-kv.x, d1 = qpf[q*4+1]-kv.y, d2 = qpf[q*4+2]-kv.z, d3 = qpf[q*4+3]-kv.w;
            dist += d0*d0 + d1*d1 + d2*d2 + d3*d3;
        }
        float l = qk - pwv*dist + (bias + bpbv)*PAIR_SCALE;

        // online softmax update (per wave)
        float cm = l;
        #pragma unroll
        for (int off = 1; off < 64; off <<= 1) cm = fmaxf(cm, __shfl_xor(cm, off));
        float mn = fmaxf(m, cm);
        float scale = __expf(m - mn);
        m = mn;
        float e = __expf(l - m);
        float cs = e;
        #pragma unroll
        for (int off = 1; off < 64; off <<= 1) cs += __shfl_xor(cs, off);
        s = s*scale + cs;
        attE[h*64 + lane] = e;
        r0 *= scale; r1 *= scale; rsv *= scale;

        // accumulate res_e (all lanes) from LDS
        const float* aE = &attE[h*64];
        const float* ecl = &ech[lane];
        #pragma unroll 8
        for (int jj = 0; jj < 64; jj++) {
            float a = aE[jj];
            r0 += a * ecl[jj*132];
            r1 += a * ecl[jj*132 + 64];
        }
        // accumulate res_s / res_p (lanes 0..27) from global (L2-hot)
        if (lane < 28) {
            const float* vp0 = vsrc + (size_t)(cc*64) * vstride;
            #pragma unroll 8
            for (int jj = 0; jj < 64; jj++) rsv += aE[jj] * vp0[(size_t)jj*vstride];
        }
        __syncthreads();
    }

    const float inv = 1.f / s;
    r0 *= inv; r1 *= inv; rsv *= inv;
    float* cg = cat + (size_t)g*1280;
    cg[256 + h*128 + lane]      = r0;
    cg[256 + h*128 + 64 + lane] = r1;
    if (lane < 16) cg[h*16 + lane] = rsv;
    else if (lane < 28) {
        int idx = lane - 16;               // p*3 + rr
        rpL[h*12 + idx] = rsv - trans[(size_t)g*3 + idx % 3];
    }
    __syncthreads();
    if (t < 96) {
        int hh = t/12, rem = t%12, rr = rem%3;
        const float* rp = &rpL[hh*12 + (rem/3)*3];
        const float* rm = rot + (size_t)g*9 + rr*3;
        float v = rp[0]*rm[0] + rp[1]*rm[1] + rp[2]*rm[2];
        rpsL[t] = v;
        cg[128 + t] = v;
    }
    __syncthreads();
    if (t < 32) {
        int hh = t >> 2, p = t & 3;
        const float* v = &rpsL[hh*12 + p*3];
        cg[224 + t] = sqrtf(v[0]*v[0] + v[1]*v[1] + v[2]*v[2] + 1e-8f);
    }
}

// =====================================================================
// K4: MFMA GEMM  C[M,N] = A[M,K](f32) @ Wt[N,K](bf16)^T + bias, opt relu
// BM=BN=64, BK=32, 256 threads = 4 waves (2x2), wave tile 32x32.
// =====================================================================
template<bool RELU>
__global__ __launch_bounds__(256) void k_gemm_mfma(
    const float* __restrict__ A, const unsigned short* __restrict__ Bt,
    const float* __restrict__ bias, float* __restrict__ C,
    int M, int Ncol, int K)
{
    __shared__ __align__(16) unsigned short As[64*40];
    __shared__ __align__(16) unsigned short Bs[64*40];
    const int t = threadIdx.x;
    const int ntile = Ncol >> 6;
    const int m0 = (blockIdx.x / ntile) << 6;
    const int n0 = (blockIdx.x % ntile) << 6;
    const int w = t >> 6, lane = t & 63;
    const int wr = (w >> 1) * 32, wc = (w & 1) * 32;
    const int frow = lane & 15, kgrp = (lane >> 4) * 8;
    const int srow = t >> 2, sk = (t & 3) * 8;

    f32x4 acc[2][2];
    #pragma unroll
    for (int a = 0; a < 2; a++)
        #pragma unroll
        for (int c = 0; c < 2; c++) acc[a][c] = (f32x4){0.f, 0.f, 0.f, 0.f};

    for (int k0 = 0; k0 < K; k0 += 32) {
        const float* ap = A + (size_t)(m0 + srow)*K + k0 + sk;
        float4 a0 = *reinterpret_cast<const float4*>(ap);
        float4 a1 = *reinterpret_cast<const float4*>(ap + 4);
        us8 av;
        av[0] = f2b(a0.x); av[1] = f2b(a0.y); av[2] = f2b(a0.z); av[3] = f2b(a0.w);
        av[4] = f2b(a1.x); av[5] = f2b(a1.y); av[6] = f2b(a1.z); av[7] = f2b(a1.w);
        *reinterpret_cast<us8*>(&As[srow*40 + sk]) = av;
        *reinterpret_cast<us8*>(&Bs[srow*40 + sk]) =
            *reinterpret_cast<const us8*>(Bt + (size_t)(n0 + srow)*K + k0 + sk);
        __syncthreads();
        bf16x8 af0 = *reinterpret_cast<const bf16x8*>(&As[(wr + frow)*40 + kgrp]);
        bf16x8 af1 = *reinterpret_cast<const bf16x8*>(&As[(wr + 16 + frow)*40 + kgrp]);
        bf16x8 bf0 = *reinterpret_cast<const bf16x8*>(&Bs[(wc + frow)*40 + kgrp]);
        bf16x8 bf1 = *reinterpret_cast<const bf16x8*>(&Bs[(wc + 16 + frow)*40 + kgrp]);
        acc[0][0] = __builtin_amdgcn_mfma_f32_16x16x32_bf16(af0, bf0, acc[0][0], 0, 0, 0);
        acc[0][1] = __builtin_amdgcn_mfma_f32_16x16x32_bf16(af0, bf1, acc[0][1], 0, 0, 0);
        acc[1][0] = __builtin_amdgcn_mfma_f32_16x16x32_bf16(af1, bf0, acc[1][0], 0, 0, 0);
        acc[1][1] = __builtin_amdgcn_mfma_f32_16x16x32_bf16(af1, bf1, acc[1][1], 0, 0, 0);
        __syncthreads();
    }

    #pragma unroll
    for (int fi = 0; fi < 2; fi++) {
        #pragma unroll
        for (int fj = 0; fj < 2; fj++) {
            int row = m0 + wr + fi*16 + (lane >> 4)*4;
            int col = n0 + wc + fj*16 + (lane & 15);
            float bv = bias[col];
            #pragma unroll
            for (int r = 0; r < 4; r++) {
                float v = acc[fi][fj][r] + bv;
                if (RELU) v = fmaxf(v, 0.f);
                C[(size_t)(row + r)*Ncol + col] = v;
            }
        }
    }
}

// =====================================================================
// K5: LayerNorm over D=384. 1 wave per row.
// =====================================================================
__global__ __launch_bounds__(64) void k_ln(
    const float* __restrict__ X, const float* __restrict__ gam, const float* __restrict__ bet,
    float* __restrict__ Y)
{
    const int t = threadIdx.x, g = blockIdx.x;
    const float* x = X + (size_t)g*384;
    float v[6]; float s = 0.f, s2 = 0.f;
    #pragma unroll
    for (int k = 0; k < 6; k++) { v[k] = x[t + 64*k]; s += v[k]; s2 += v[k]*v[k]; }
    #pragma unroll
    for (int off = 1; off < 64; off <<= 1) { s += __shfl_xor(s, off); s2 += __shfl_xor(s2, off); }
    float mu = s * (1.f/384.f);
    float var = s2 * (1.f/384.f) - mu*mu;
    float rs = rsqrtf(var + 1e-5f);
    float* y = Y + (size_t)g*384;
    #pragma unroll
    for (int k = 0; k < 6; k++) { int d = t + 64*k; y[d] = (v[k]-mu)*rs*gam[d] + bet[d]; }
}

// =====================================================================
extern "C" void kernel_launch(void* const* d_in, const int* in_sizes, int n_in,
                              void* d_out, int out_size, void* d_ws, size_t ws_size,
                              hipStream_t stream)
{
    const float* node = (const float*)d_in[0];
    const float* edge = (const float*)d_in[1];
    const float* rot  = (const float*)d_in[2];
    const float* trans= (const float*)d_in[3];
    const float* Wq  = (const float*)d_in[5];
    const float* Wk  = (const float*)d_in[6];
    const float* Wv  = (const float*)d_in[7];
    const float* Wpq = (const float*)d_in[8];
    const float* Wpk = (const float*)d_in[9];
    const float* Wpv = (const float*)d_in[10];
    const float* pt_w= (const float*)d_in[11];
    const float* Wpb = (const float*)d_in[12];
    const float* bpb = (const float*)d_in[13];
    const float* Wo  = (const float*)d_in[14];
    const float* bo  = (const float*)d_in[15];
    const float* ln1g= (const float*)d_in[16];
    const float* ln1b= (const float*)d_in[17];
    const float* W1  = (const float*)d_in[18];
    const float* b1  = (const float*)d_in[19];
    const float* W2  = (const float*)d_in[20];
    const float* b2  = (const float*)d_in[21];
    const float* W3  = (const float*)d_in[22];
    const float* b3  = (const float*)d_in[23];
    const float* ln2g= (const float*)d_in[24];
    const float* ln2b= (const float*)d_in[25];

    float* ws = (float*)d_ws;
    float* qs   = ws;                  // 131072
    float* ks   = qs + 131072;         // 131072
    float* vs   = ks + 131072;         // 131072
    float* qp   = vs + 131072;         // 98304
    float* kp   = qp + 98304;          // 98304
    float* vp   = kp + 98304;          // 98304
    float* cat  = vp + 98304;          // 1310720  (ends 1998848)
    float* x0   = cat + 1310720;       // 393216
    float* xln  = x0 + 393216;         // 393216
    float* h1   = xln + 393216;        // 786432
    float* h2   = h1 + 786432;         // 786432
    float* x3   = h2 + 786432;         // 393216  (ends 4751360 floats = 19.0 MB)
    unsigned short* wt0 = (unsigned short*)(ws + 4751360);  // 384*1280
    unsigned short* wt1 = wt0 + 491520;                      // 768*384
    unsigned short* wt2 = wt1 + 294912;                      // 768*768
    unsigned short* wt3 = wt2 + 589824;                      // 384*768  (total ~22.4 MB)
    float* out = (float*)d_out;

    k_prepw<<<(1280/32)*(384/32), 256, 0, stream>>>(Wo, wt0, 1280, 384);
    k_prepw<<<(384/32)*(768/32),  256, 0, stream>>>(W1, wt1, 384, 768);
    k_prepw<<<(768/32)*(768/32),  256, 0, stream>>>(W2, wt2, 768, 768);
    k_prepw<<<(768/32)*(384/32),  256, 0, stream>>>(W3, wt3, 768, 384);

    k_proj<<<128, 256, 0, stream>>>(node, rot, trans, Wq, Wk, Wv, Wpq, Wpk, Wpv,
                                    qs, ks, vs, qp, kp, vp);
    k_attn<<<1024, 512, 0, stream>>>(edge, qs, ks, qp, kp, vs, vp, rot, trans,
                                     pt_w, Wpb, bpb, cat);

    k_gemm_mfma<false><<<16*6,  256, 0, stream>>>(cat, wt0, bo, x0, 1024, 384, 1280);
    k_ln<<<1024, 64, 0, stream>>>(x0, ln1g, ln1b, xln);
    k_gemm_mfma<true ><<<16*12, 256, 0, stream>>>(xln, wt1, b1, h1, 1024, 768, 384);
    k_gemm_mfma<true ><<<16*12, 256, 0, stream>>>(h1, wt2, b2, h2, 1024, 768, 768);
    k_gemm_mfma<false><<<16*6,  256, 0, stream>>>(h2, wt3, b3, x3, 1024, 384, 768);
    k_ln<<<1024, 64, 0, stream>>>(x3, ln2g, ln2b, out);
}

// Round 10
// 603.936 us; speedup vs baseline: 1.3552x; 1.1933x over previous
//
#include <hip/hip_runtime.h>
#include <cstdint>
#include <cstddef>

// ---- problem constants ----
// B=2 N=512 D=384 E=128 H=8 SK=SV=16 PK=PV=4 DH=768 CAT=1280
constexpr float SCALAR_SCALE = 0.14433756729740643f;  // (3*16)^-0.5
constexpr float POINT_SCALE  = 0.13608276348795434f;  // (3*4*4.5)^-0.5
constexpr float PAIR_SCALE   = 0.57735026918962576f;  // 3^-0.5

typedef float  f32x4  __attribute__((ext_vector_type(4)));
typedef short  bf16x8 __attribute__((ext_vector_type(8)));
typedef unsigned short us8 __attribute__((ext_vector_type(8)));
typedef unsigned short us4 __attribute__((ext_vector_type(4)));

__device__ __forceinline__ unsigned short f2b(float f) {
    union { float f; uint32_t u; } v; v.f = f;
    uint32_t u = v.u;
    return (unsigned short)((u + 0x7FFFu + ((u >> 16) & 1u)) >> 16);
}

// =====================================================================
// K0: weight prep — W[K][N] f32 -> Wt[N][K] bf16 (32x32 tiles)
// =====================================================================
__global__ __launch_bounds__(256) void k_prepw(
    const float* __restrict__ W, unsigned short* __restrict__ Wt, int K, int N)
{
    __shared__ float L[32][33];
    const int ntile = N >> 5;
    const int kt = (blockIdx.x / ntile) << 5;
    const int nt = (blockIdx.x % ntile) << 5;
    const int t = threadIdx.x;
    const int row = t >> 3, col4 = (t & 7) * 4;
    float4 v = *reinterpret_cast<const float4*>(W + (size_t)(kt + row) * N + nt + col4);
    L[row][col4+0] = v.x; L[row][col4+1] = v.y; L[row][col4+2] = v.z; L[row][col4+3] = v.w;
    __syncthreads();
    us4 o;
    o[0] = f2b(L[col4+0][row]);
    o[1] = f2b(L[col4+1][row]);
    o[2] = f2b(L[col4+2][row]);
    o[3] = f2b(L[col4+3][row]);
    *reinterpret_cast<us4*>(Wt + (size_t)(nt + row) * K + kt + col4) = o;
}

// =====================================================================
// K4: MFMA GEMM  C[M,N] = A[M,K](f32) @ Wt[N,K](bf16)^T [+ bias][relu]
// BM=BN=64, BK=32, 256 threads = 4 waves (2x2), wave tile 32x32.
// =====================================================================
template<bool RELU, bool BIAS>
__global__ __launch_bounds__(256) void k_gemm_mfma(
    const float* __restrict__ A, const unsigned short* __restrict__ Bt,
    const float* __restrict__ bias, float* __restrict__ C,
    int M, int Ncol, int K)
{
    __shared__ __align__(16) unsigned short As[64*40];
    __shared__ __align__(16) unsigned short Bs[64*40];
    const int t = threadIdx.x;
    const int ntile = Ncol >> 6;
    const int m0 = (blockIdx.x / ntile) << 6;
    const int n0 = (blockIdx.x % ntile) << 6;
    const int w = t >> 6, lane = t & 63;
    const int wr = (w >> 1) * 32, wc = (w & 1) * 32;
    const int frow = lane & 15, kgrp = (lane >> 4) * 8;
    const int srow = t >> 2, sk = (t & 3) * 8;

    f32x4 acc[2][2];
    #pragma unroll
    for (int a = 0; a < 2; a++)
        #pragma unroll
        for (int c = 0; c < 2; c++) acc[a][c] = (f32x4){0.f, 0.f, 0.f, 0.f};

    for (int k0 = 0; k0 < K; k0 += 32) {
        const float* ap = A + (size_t)(m0 + srow)*K + k0 + sk;
        float4 a0 = *reinterpret_cast<const float4*>(ap);
        float4 a1 = *reinterpret_cast<const float4*>(ap + 4);
        us8 av;
        av[0] = f2b(a0.x); av[1] = f2b(a0.y); av[2] = f2b(a0.z); av[3] = f2b(a0.w);
        av[4] = f2b(a1.x); av[5] = f2b(a1.y); av[6] = f2b(a1.z); av[7] = f2b(a1.w);
        *reinterpret_cast<us8*>(&As[srow*40 + sk]) = av;
        *reinterpret_cast<us8*>(&Bs[srow*40 + sk]) =
            *reinterpret_cast<const us8*>(Bt + (size_t)(n0 + srow)*K + k0 + sk);
        __syncthreads();
        bf16x8 af0 = *reinterpret_cast<const bf16x8*>(&As[(wr + frow)*40 + kgrp]);
        bf16x8 af1 = *reinterpret_cast<const bf16x8*>(&As[(wr + 16 + frow)*40 + kgrp]);
        bf16x8 bf0 = *reinterpret_cast<const bf16x8*>(&Bs[(wc + frow)*40 + kgrp]);
        bf16x8 bf1 = *reinterpret_cast<const bf16x8*>(&Bs[(wc + 16 + frow)*40 + kgrp]);
        acc[0][0] = __builtin_amdgcn_mfma_f32_16x16x32_bf16(af0, bf0, acc[0][0], 0, 0, 0);
        acc[0][1] = __builtin_amdgcn_mfma_f32_16x16x32_bf16(af0, bf1, acc[0][1], 0, 0, 0);
        acc[1][0] = __builtin_amdgcn_mfma_f32_16x16x32_bf16(af1, bf0, acc[1][0], 0, 0, 0);
        acc[1][1] = __builtin_amdgcn_mfma_f32_16x16x32_bf16(af1, bf1, acc[1][1], 0, 0, 0);
        __syncthreads();
    }

    #pragma unroll
    for (int fi = 0; fi < 2; fi++) {
        #pragma unroll
        for (int fj = 0; fj < 2; fj++) {
            int row = m0 + wr + fi*16 + (lane >> 4)*4;
            int col = n0 + wc + fj*16 + (lane & 15);
            float bv = 0.f;
            if (BIAS) bv = bias[col];
            #pragma unroll
            for (int r = 0; r < 4; r++) {
                float v = acc[fi][fj][r] + bv;
                if (RELU) v = fmaxf(v, 0.f);
                C[(size_t)(row + r)*Ncol + col] = v;
            }
        }
    }
}

// =====================================================================
// K1b: post-projection scatter + point rotation.
// raw[g][0..672]: 0-127 qs | 128-255 ks | 256-383 vs | 384-671 points
// block = token g, 384 threads.
// =====================================================================
__global__ __launch_bounds__(384) void k_post(
    const float* __restrict__ raw, const float* __restrict__ rot, const float* __restrict__ trans,
    float* __restrict__ qs, float* __restrict__ ks, float* __restrict__ vs,
    float* __restrict__ qp, float* __restrict__ kp, float* __restrict__ vp)
{
    __shared__ __align__(16) float rawL[672];
    __shared__ float rotL[9];
    __shared__ float trL[3];
    const int t = threadIdx.x, g = blockIdx.x, b = g >> 9, i = g & 511;

    if (t < 168)
        reinterpret_cast<float4*>(rawL)[t] =
            reinterpret_cast<const float4*>(raw + (size_t)g*704)[t];
    else if (t < 177) rotL[t-168] = rot[(size_t)g*9 + (t-168)];
    else if (t < 180) trL[t-177]  = trans[(size_t)g*3 + (t-177)];
    __syncthreads();

    if (t < 128) qs[(size_t)g*128 + t] = rawL[t];
    else if (t < 256) { int idx = t-128, h = idx>>4, d = idx&15;
        ks[(((size_t)(b*8+h))*512 + i)*16 + d] = rawL[t]; }
    else { int idx = t-256, h = idx>>4, d = idx&15;
        vs[(((size_t)(b*8+h))*512 + i)*16 + d] = rawL[t]; }

    if (t < 288) {
        int which = t/96, idx = t%96;
        int h = idx/12, rem = idx%12, pp = rem/3, rr = rem%3;
        const float* rw = &rawL[384 + which*96 + h*12 + pp*3];
        float v = rw[0]*rotL[0*3+rr] + rw[1]*rotL[1*3+rr] + rw[2]*rotL[2*3+rr] + trL[rr];
        if (which == 0)      qp[(size_t)g*96 + idx] = v;
        else if (which == 1) kp[((((size_t)(b*8+h))*512 + i)*4 + pp)*3 + rr] = v;
        else                 vp[((((size_t)(b*8+h))*512 + i)*4 + pp)*3 + rr] = v;
    }
}

// =====================================================================
// K2: fused attention. block=(b,i), 512 threads (wave = head h).
// Single pass over edge with online softmax. Staging is immediate
// load->LDS (NO cross-barrier register hold — r8 spill post-mortem:
// holding 16 VGPRs across the barrier spilled ~30 regs/thread = 245 MB
// of scratch writes/dispatch. VGPR must stay ~64.)
// =====================================================================
__global__ __launch_bounds__(512) void k_attn(
    const float* __restrict__ edge, const float* __restrict__ qs,
    const float* __restrict__ ks, const float* __restrict__ qp, const float* __restrict__ kp,
    const float* __restrict__ vs, const float* __restrict__ vp,
    const float* __restrict__ rot, const float* __restrict__ trans,
    const float* __restrict__ pt_w, const float* __restrict__ Wpb, const float* __restrict__ bpb,
    float* __restrict__ cat)
{
    __shared__ __align__(16) float ech[64*132];   // 64 j x 128 d, stride 132
    __shared__ float attE[8*64];
    __shared__ float wpbL[128*8];
    __shared__ float qsL[128];
    __shared__ float qpL[96];
    __shared__ float pwL[8];
    __shared__ float bpbL[8];
    __shared__ float rpL[96];
    __shared__ float rpsL[96];

    const int t = threadIdx.x;
    const int g = blockIdx.x, b = g >> 9;

    wpbL[t] = Wpb[t];
    wpbL[t + 512] = Wpb[t + 512];
    if (t < 128) qsL[t] = qs[(size_t)g*128 + t] * SCALAR_SCALE;
    else if (t < 224) qpL[t-128] = qp[(size_t)g*96 + (t-128)];
    else if (t < 232) { float x = pt_w[t-224]; pwL[t-224] = (x > 20.f) ? x : log1pf(expf(x)); }
    else if (t < 240) bpbL[t-232] = bpb[t-232];
    __syncthreads();

    const int h = t >> 6, lane = t & 63;
    const float pwv  = pwL[h] * 0.5f * POINT_SCALE;
    const float bpbv = bpbL[h];
    float qf[16];
    #pragma unroll
    for (int d = 0; d < 16; d++) qf[d] = qsL[h*16 + d];
    float qpf[12];
    #pragma unroll
    for (int c = 0; c < 12; c++) qpf[c] = qpL[h*12 + c];

    const float4* ef4 = reinterpret_cast<const float4*>(edge) + (size_t)g*16384;
    const float4* kr4 = reinterpret_cast<const float4*>(ks + (((size_t)(b*8+h))*512)*16);
    const float*  kpb = kp + (((size_t)(b*8+h))*512)*12;

    // v-source for res_s (lanes 0..15) / res_p (lanes 16..27)
    const float* vsrc = nullptr; int vstride = 0;
    if (lane < 16)      { vsrc = vs + (((size_t)(b*8+h))*512)*16 + lane;      vstride = 16; }
    else if (lane < 28) { vsrc = vp + (((size_t)(b*8+h))*512)*12 + (lane-16); vstride = 12; }

    float m = -1e30f, s = 0.f, r0 = 0.f, r1 = 0.f, rsv = 0.f;

    for (int cc = 0; cc < 8; cc++) {
        // stage chunk cc: load + immediate scatter (no cross-barrier hold)
        {
            float4 v0 = ef4[cc*2048 + t];
            float4 v1 = ef4[cc*2048 + t + 512];
            float4 v2 = ef4[cc*2048 + t + 1024];
            float4 v3 = ef4[cc*2048 + t + 1536];
            int j0 = t >> 5,          d0 = (t & 31) * 4;
            *reinterpret_cast<float4*>(&ech[j0*132 + d0])        = v0;
            *reinterpret_cast<float4*>(&ech[(j0+16)*132 + d0])   = v1;
            *reinterpret_cast<float4*>(&ech[(j0+32)*132 + d0])   = v2;
            *reinterpret_cast<float4*>(&ech[(j0+48)*132 + d0])   = v3;
        }
        __syncthreads();

        const int j = cc*64 + lane;
        // pair bias: edge[j,:] . Wpb[:,h]
        const float4* er4 = reinterpret_cast<const float4*>(&ech[lane*132]);
        float b0=0.f, b1=0.f, b2=0.f, b3=0.f;
        #pragma unroll 8
        for (int d4 = 0; d4 < 32; d4++) {
            float4 e = er4[d4];
            b0 += e.x * wpbL[(d4*4+0)*8 + h];
            b1 += e.y * wpbL[(d4*4+1)*8 + h];
            b2 += e.z * wpbL[(d4*4+2)*8 + h];
            b3 += e.w * wpbL[(d4*4+3)*8 + h];
        }
        float bias = (b0+b1) + (b2+b3);
        // scalar qk (qf prescaled)
        float qk = 0.f;
        #pragma unroll
        for (int q = 0; q < 4; q++) {
            float4 kv = kr4[j*4 + q];
            qk += qf[q*4+0]*kv.x + qf[q*4+1]*kv.y + qf[q*4+2]*kv.z + qf[q*4+3]*kv.w;
        }
        // point distance
        const float4* kp4 = reinterpret_cast<const float4*>(kpb + j*12);
        float dist = 0.f;
        #pragma unroll
        for (int q = 0; q < 3; q++) {
            float4 kv = kp4[q];
            float d0 = qpf[q*4+0]-kv.x, d1 = qpf[q*4+1]-kv.y, d2 = qpf[q*4+2]-kv.z, d3 = qpf[q*4+3]-kv.w;
            dist += d0*d0 + d1*d1 + d2*d2 + d3*d3;
        }
        float l = qk - pwv*dist + (bias + bpbv)*PAIR_SCALE;

        // online softmax update (per wave)
        float cm = l;
        #pragma unroll
        for (int off = 1; off < 64; off <<= 1) cm = fmaxf(cm, __shfl_xor(cm, off));
        float mn = fmaxf(m, cm);
        float scale = __expf(m - mn);
        m = mn;
        float e = __expf(l - m);
        float cs = e;
        #pragma unroll
        for (int off = 1; off < 64; off <<= 1) cs += __shfl_xor(cs, off);
        s = s*scale + cs;
        attE[h*64 + lane] = e;
        r0 *= scale; r1 *= scale; rsv *= scale;

        // accumulate res_e (all lanes) from LDS
        const float* aE = &attE[h*64];
        const float* ecl = &ech[lane];
        #pragma unroll 8
        for (int jj = 0; jj < 64; jj++) {
            float a = aE[jj];
            r0 += a * ecl[jj*132];
            r1 += a * ecl[jj*132 + 64];
        }
        // accumulate res_s / res_p (lanes 0..27) from global (L2-hot)
        if (lane < 28) {
            const float* vp0 = vsrc + (size_t)(cc*64) * vstride;
            #pragma unroll 8
            for (int jj = 0; jj < 64; jj++) rsv += aE[jj] * vp0[(size_t)jj*vstride];
        }
        __syncthreads();
    }

    const float inv = 1.f / s;
    r0 *= inv; r1 *= inv; rsv *= inv;
    float* cg = cat + (size_t)g*1280;
    cg[256 + h*128 + lane]      = r0;
    cg[256 + h*128 + 64 + lane] = r1;
    if (lane < 16) cg[h*16 + lane] = rsv;
    else if (lane < 28) {
        int idx = lane - 16;               // p*3 + rr
        rpL[h*12 + idx] = rsv - trans[(size_t)g*3 + idx % 3];
    }
    __syncthreads();
    if (t < 96) {
        int hh = t/12, rem = t%12, rr = rem%3;
        const float* rp = &rpL[hh*12 + (rem/3)*3];
        const float* rm = rot + (size_t)g*9 + rr*3;
        float v = rp[0]*rm[0] + rp[1]*rm[1] + rp[2]*rm[2];
        rpsL[t] = v;
        cg[128 + t] = v;
    }
    __syncthreads();
    if (t < 32) {
        int hh = t >> 2, p = t & 3;
        const float* v = &rpsL[hh*12 + p*3];
        cg[224 + t] = sqrtf(v[0]*v[0] + v[1]*v[1] + v[2]*v[2] + 1e-8f);
    }
}

// =====================================================================
// K5: LayerNorm over D=384. 1 wave per row.
// =====================================================================
__global__ __launch_bounds__(64) void k_ln(
    const float* __restrict__ X, const float* __restrict__ gam, const float* __restrict__ bet,
    float* __restrict__ Y)
{
    const int t = threadIdx.x, g = blockIdx.x;
    const float* x = X + (size_t)g*384;
    float v[6]; float s = 0.f, s2 = 0.f;
    #pragma unroll
    for (int k = 0; k < 6; k++) { v[k] = x[t + 64*k]; s += v[k]; s2 += v[k]*v[k]; }
    #pragma unroll
    for (int off = 1; off < 64; off <<= 1) { s += __shfl_xor(s, off); s2 += __shfl_xor(s2, off); }
    float mu = s * (1.f/384.f);
    float var = s2 * (1.f/384.f) - mu*mu;
    float rs = rsqrtf(var + 1e-5f);
    float* y = Y + (size_t)g*384;
    #pragma unroll
    for (int k = 0; k < 6; k++) { int d = t + 64*k; y[d] = (v[k]-mu)*rs*gam[d] + bet[d]; }
}

// =====================================================================
extern "C" void kernel_launch(void* const* d_in, const int* in_sizes, int n_in,
                              void* d_out, int out_size, void* d_ws, size_t ws_size,
                              hipStream_t stream)
{
    const float* node = (const float*)d_in[0];
    const float* edge = (const float*)d_in[1];
    const float* rot  = (const float*)d_in[2];
    const float* trans= (const float*)d_in[3];
    const float* Wq  = (const float*)d_in[5];
    const float* Wk  = (const float*)d_in[6];
    const float* Wv  = (const float*)d_in[7];
    const float* Wpq = (const float*)d_in[8];
    const float* Wpk = (const float*)d_in[9];
    const float* Wpv = (const float*)d_in[10];
    const float* pt_w= (const float*)d_in[11];
    const float* Wpb = (const float*)d_in[12];
    const float* bpb = (const float*)d_in[13];
    const float* Wo  = (const float*)d_in[14];
    const float* bo  = (const float*)d_in[15];
    const float* ln1g= (const float*)d_in[16];
    const float* ln1b= (const float*)d_in[17];
    const float* W1  = (const float*)d_in[18];
    const float* b1  = (const float*)d_in[19];
    const float* W2  = (const float*)d_in[20];
    const float* b2  = (const float*)d_in[21];
    const float* W3  = (const float*)d_in[22];
    const float* b3  = (const float*)d_in[23];
    const float* ln2g= (const float*)d_in[24];
    const float* ln2b= (const float*)d_in[25];

    float* ws = (float*)d_ws;
    float* qs   = ws;                  // 131072
    float* ks   = qs + 131072;         // 131072
    float* vs   = ks + 131072;         // 131072
    float* qp   = vs + 131072;         // 98304
    float* kp   = qp + 98304;          // 98304
    float* vp   = kp + 98304;          // 98304
    float* cat  = vp + 98304;          // 1310720  (ends 1998848)
    float* x0   = cat + 1310720;       // 393216
    float* xln  = x0 + 393216;         // 393216
    float* h1   = xln + 393216;        // 786432
    float* h2   = h1 + 786432;         // 786432
    float* x3   = h2 + 786432;         // 393216  (ends 4751360 floats)
    unsigned short* wt0 = (unsigned short*)(ws + 4751360);  // 384*1280 shorts
    unsigned short* wt1 = wt0 + 491520;                      // 768*384
    unsigned short* wt2 = wt1 + 294912;                      // 768*768
    unsigned short* wt3 = wt2 + 589824;                      // 384*768
    unsigned short* wcat = wt3 + 294912;                     // 704*384 shorts
    float* raw  = ws + 5722112;        // 1024*704 f32 (ends 6443008 floats ~25.8 MB)
    float* out = (float*)d_out;

    // weight prep
    k_prepw<<<(1280/32)*(384/32), 256, 0, stream>>>(Wo, wt0, 1280, 384);
    k_prepw<<<(384/32)*(768/32),  256, 0, stream>>>(W1, wt1, 384, 768);
    k_prepw<<<(768/32)*(768/32),  256, 0, stream>>>(W2, wt2, 768, 768);
    k_prepw<<<(768/32)*(384/32),  256, 0, stream>>>(W3, wt3, 768, 384);
    // concat projection weights -> wcat[704][384] (rows 672-703 unused)
    k_prepw<<<(384/32)*(128/32), 256, 0, stream>>>(Wq,  wcat,            384, 128);
    k_prepw<<<(384/32)*(128/32), 256, 0, stream>>>(Wk,  wcat + 128*384,  384, 128);
    k_prepw<<<(384/32)*(128/32), 256, 0, stream>>>(Wv,  wcat + 256*384,  384, 128);
    k_prepw<<<(384/32)*(96/32),  256, 0, stream>>>(Wpq, wcat + 384*384,  384, 96);
    k_prepw<<<(384/32)*(96/32),  256, 0, stream>>>(Wpk, wcat + 480*384,  384, 96);
    k_prepw<<<(384/32)*(96/32),  256, 0, stream>>>(Wpv, wcat + 576*384,  384, 96);

    // projections as one MFMA GEMM + scatter/rotate
    k_gemm_mfma<false,false><<<16*11, 256, 0, stream>>>(node, wcat, nullptr, raw, 1024, 704, 384);
    k_post<<<1024, 384, 0, stream>>>(raw, rot, trans, qs, ks, vs, qp, kp, vp);

    k_attn<<<1024, 512, 0, stream>>>(edge, qs, ks, qp, kp, vs, vp, rot, trans,
                                     pt_w, Wpb, bpb, cat);

    k_gemm_mfma<false,true><<<16*6,  256, 0, stream>>>(cat, wt0, bo, x0, 1024, 384, 1280);
    k_ln<<<1024, 64, 0, stream>>>(x0, ln1g, ln1b, xln);
    k_gemm_mfma<true,true ><<<16*12, 256, 0, stream>>>(xln, wt1, b1, h1, 1024, 768, 384);
    k_gemm_mfma<true,true ><<<16*12, 256, 0, stream>>>(h1, wt2, b2, h2, 1024, 768, 768);
    k_gemm_mfma<false,true><<<16*6,  256, 0, stream>>>(h2, wt3, b3, x3, 1024, 384, 768);
    k_ln<<<1024, 64, 0, stream>>>(x3, ln2g, ln2b, out);
}